// Round 9
// baseline (7675.363 us; speedup 1.0000x reference)
//
#include <hip/hip_runtime.h>
#include <hip/hip_bf16.h>

// LSTM: B=64, D=32, H=512, T=1024. gates = [h,x] @ [W_hh;W_ih]^T + b_ih + b_hh
// Round 22: DUAL-CHAIN latency hiding, conservative sync. 64 blocks =
// 2 gpairs x 32 slices, 256 thr (4 waves). Each block time-shares two
// independent group recurrences (gA=gp*2, gB=gp*2+1): probes for one chain
// fly through the IC while the block computes the other chain. All waits are
// plain waitvm0 (no FIFO counting -- safe w.r.t. compiler-inserted weight
// reloads, cf. R21 post-mortem), probes issued only at phase boundaries,
// sched_barrier(0) after waits (rule 18). Poll loops are the R13-validated
// unbounded device-scope kind; deadlock-free (minimal-stuck-point: every
// wait targets packets published strictly earlier). Per-chain microkernel,
// transport, tags (bit16 ring-2), staging math BYTE-IDENTICAL to validated
// R20 (32 slices of 16 units, 51 MFMAs/wave, lane-local epilogue).
// LDS: hsA+hsB 64KB (single-buffered; epochs separated by the other chain's
// barrier) + pjA+pjB 16KB = 80KB.

typedef unsigned short ushort_t;
typedef unsigned int   uint_t;
typedef unsigned long long u64_t;
typedef __attribute__((ext_vector_type(8))) short bf16x8;
typedef __attribute__((ext_vector_type(4))) float f32x4;
typedef __attribute__((ext_vector_type(4))) uint_t u32x4;

#define T_STEPS 1024
#define HID     512
#define KDIM    544   // 512 h + 32 x
#define NBLK    64    // 2 gpairs * 32 slices
#define NTHR    256   // 4 waves

__device__ inline ushort_t f2bf(float x) {
    __hip_bfloat16 h = __float2bfloat16(x);
    return *(ushort_t*)&h;
}
__device__ inline float bf2f(ushort_t u) {
    __hip_bfloat16 h = *(__hip_bfloat16*)&u;
    return __bfloat162float(h);
}

__device__ inline f32x4 MFMA(bf16x8 a, bf16x8 b, f32x4 c) {
    return __builtin_amdgcn_mfma_f32_16x16x32_bf16(a, b, c, 0, 0, 0);
}

// coherent 16B load / 4B store (L1+L2 bypass, meets at Infinity Cache)
__device__ inline u32x4 cld16(const void* p) {
    u32x4 v;
    asm volatile("global_load_dwordx4 %0, %1, off sc0 sc1"
                 : "=v"(v) : "v"(p) : "memory");
    return v;
}
__device__ inline void cst4(void* p, uint_t v) {
    asm volatile("global_store_dword %0, %1, off sc0 sc1"
                 :: "v"(p), "v"(v) : "memory");
}
__device__ inline void waitvm0() {
    asm volatile("s_waitcnt vmcnt(0)" ::: "memory");
}

// is_tanh: tanh(v)=(1-e)/(1+e), e=2^(-2.885*v); sigmoid(v)=1/(1+e), e=2^(-1.4427*v)
__device__ inline float act_gate(float v, int is_tanh) {
    float vc = fminf(fmaxf(v, -43.f), 43.f);
    float kk = is_tanh ? -2.88539008f : -1.44269504f;
    float e  = __builtin_exp2f(vc * kk);
    float num = is_tanh ? (1.f - e) : 1.f;
    return num * __builtin_amdgcn_rcpf(1.f + e);
}

// ---------- prep kernels ----------

__global__ void k_init(uint_t* hx32) {
    int i = blockIdx.x * 256 + threadIdx.x;      // grid 256x256 = 65536
    // init h ring: value ~0 (denormal bf16), tag bit16 = 1 (differs from tag 0
    // expected at t=1/t=2) -> no ABA with init data.
    hx32[i] = 0x00010000u;                       // 2*4*128*16 x 16B = 65536 u32
}

__global__ void k_wcat(const float* __restrict__ wih, const float* __restrict__ whh,
                       ushort_t* __restrict__ wh, ushort_t* __restrict__ wl) {
    int r = blockIdx.x;                          // 2048 gate rows
    for (int k = threadIdx.x; k < KDIM; k += 256) {
        float w = (k < 512) ? whh[r * 512 + k] : wih[r * 32 + (k - 512)];
        ushort_t hh = f2bf(w);
        ushort_t ll = f2bf(w - bf2f(hh));
        wh[r * KDIM + k] = hh;
        wl[r * KDIM + k] = ll;
    }
}

// input (B=64, D=32, T=1024) fp32 -> xbuf[t][b][d] bf16 hi/lo
__global__ void k_xbuf(const float* __restrict__ in,
                       ushort_t* __restrict__ xh, ushort_t* __restrict__ xl) {
    __shared__ float tile[64][65];
    int bp = blockIdx.x >> 4;                    // batch pair 0..31
    int tt = blockIdx.x & 15;                    // t tile 0..15
    int t0 = tt * 64;
    int wv = threadIdx.x >> 6, l = threadIdx.x & 63;
    for (int r = wv * 16; r < wv * 16 + 16; r++) {
        int b = bp * 2 + (r >> 5), d = r & 31;
        tile[r][l] = in[(b * 32 + d) * 1024 + t0 + l];
    }
    __syncthreads();
    for (int i = 0; i < 16; i++) {
        int tl = wv * 16 + i;
        float v = tile[l][tl];
        ushort_t hh = f2bf(v);
        ushort_t ll = f2bf(v - bf2f(hh));
        int o = (t0 + tl) * 2048 + bp * 64 + l;  // = t*64*32 + b*32 + d
        xh[o] = hh;
        xl[o] = ll;
    }
}

// out[b][t] = conv_b + sum_s part[(g*32+s)*16 + bl][t]   (b = g*16+bl)
__global__ void k_reduce(const float* __restrict__ part, float* __restrict__ out,
                         const float* __restrict__ cvb) {
    int b = blockIdx.x >> 2;                     // 0..63
    int t = (blockIdx.x & 3) * 256 + threadIdx.x;
    int g = b >> 4, bl = b & 15;
    const float* p = part + ((size_t)(g * 32 * 16 + bl)) * 1024 + t;
    float sum = 0.f;
    #pragma unroll
    for (int s = 0; s < 32; s++) sum += p[(size_t)s * 16 * 1024];
    out[b * 1024 + t] = sum + cvb[0];
}

// ---------- main recurrent kernel ----------

// stage 8 packets (regs) -> LDS, deinterleaving (hi,lo)x4 units
#define STAGE(HS, HV) do {                                              \
    _Pragma("unroll")                                                   \
    for (int k_ = 0; k_ < 8; k_++) {                                    \
        uint_t I0 = HV[k_][0], I1 = HV[k_][1];                          \
        uint_t I2 = HV[k_][2], I3 = HV[k_][3];                          \
        uint_t hA_ = __builtin_amdgcn_perm(I1, I0, 0x05040100u);        \
        uint_t hB_ = __builtin_amdgcn_perm(I3, I2, 0x05040100u);        \
        uint_t lA_ = __builtin_amdgcn_perm(I1, I0, 0x07060302u);        \
        uint_t lB_ = __builtin_amdgcn_perm(I3, I2, 0x07060302u);        \
        int c_  = k_ * 2 + chalf;                                       \
        int li_ = ((c_ * 4 + sq) * 16 + m16) * 2 + sd;                  \
        HS[li_]        = (u64_t)hA_ | ((u64_t)hB_ << 32);               \
        HS[li_ + 2048] = (u64_t)lA_ | ((u64_t)lB_ << 32);               \
    }                                                                   \
} while (0)

// poll-until-fresh on 8 packet regs (device-scope reload of stale ones)
#define CHECKPOLL(HV, SRC) do {                                         \
    const uint_t exp_ = ((uint_t)(((t - 1) >> 1) & 1)) << 16;           \
    for (;;) {                                                          \
        bool ok_ = true;                                                \
        _Pragma("unroll")                                               \
        for (int k_ = 0; k_ < 8; k_++) {                                \
            if (((HV[k_][0] & 0x10000u) != exp_) ||                     \
                ((HV[k_][1] & 0x10000u) != exp_) ||                     \
                ((HV[k_][2] & 0x10000u) != exp_) ||                     \
                ((HV[k_][3] & 0x10000u) != exp_)) {                     \
                HV[k_] = cld16((SRC) + k_ * 4096);                      \
                ok_ = false;                                            \
            }                                                           \
        }                                                               \
        if (ok_) break;                                                 \
        __builtin_amdgcn_s_sleep(1);                                    \
        waitvm0();                                                      \
        __builtin_amdgcn_sched_barrier(0);                              \
    }                                                                   \
} while (0)

// one MFMA K-chunk from LDS buffer HS
#define CHUNK(HS, c) do {                                               \
    frag Ah_, Al_;                                                      \
    int li_ = (((c) * 4 + q) * 16 + n) * 2;                             \
    Ah_.v = *(const bf16x8*)&HS[li_];                                   \
    Al_.v = *(const bf16x8*)&HS[li_ + 2048];                            \
    if ((c) & 1) {                                                      \
        a1 = MFMA(Bh[c], Ah_.v, a1);                                    \
        a3 = MFMA(Bl[c], Ah_.v, a3);                                    \
        a5 = MFMA(Bh[c], Al_.v, a5);                                    \
    } else {                                                            \
        a0 = MFMA(Bh[c], Ah_.v, a0);                                    \
        a2 = MFMA(Bl[c], Ah_.v, a2);                                    \
        a4 = MFMA(Bh[c], Al_.v, a4);                                    \
    }                                                                   \
} while (0)

// lane-local epilogue + publish + projection for one chain
#define EPI(Dv, CSTv, GXv, PJv) do {                                    \
    char* dst_ = hx + (size_t)((((t + 1) & 1) * 4 + (GXv)) * 128 + wg) * 256; \
    const uint_t tag_ = ((uint_t)((t >> 1) & 1)) << 16;                 \
    float iv_ = act_gate(Dv[0] + bias4[0], 0);                          \
    float fv_ = act_gate(Dv[1] + bias4[1], 0);                          \
    float gv_ = act_gate(Dv[2] + bias4[2], 1);                          \
    float ov_ = act_gate(Dv[3] + bias4[3], 0);                          \
    float cc_ = fv_ * (CSTv) + iv_ * gv_;                               \
    (CSTv) = cc_;                                                       \
    float h_ = ov_ * act_gate(cc_, 1);                                  \
    float pr_ = cw * h_;                                                \
    {                                                                   \
        ushort_t hb_ = f2bf(h_);                                        \
        uint_t word_ = (((uint_t)hb_) |                                 \
                        (((uint_t)f2bf(h_ - bf2f(hb_))) << 16)) & ~0x10000u; \
        word_ |= tag_;                                                  \
        cst4(dst_ + n * 16 + q * 4, word_);                             \
    }                                                                   \
    pr_ += __shfl_xor(pr_, 16);                                         \
    pr_ += __shfl_xor(pr_, 32);                                         \
    if (l < 16) PJv[w][l][t & 31] = pr_;                                \
    if ((t & 31) == 31) {                                               \
        __syncthreads();                                                \
        int b_ = tid >> 4, tl0_ = tid & 15;                             \
        float* dpt_ = part + (size_t)(((GXv) * 32 + s) * 16 + b_) * 1024 + (t - 31); \
        _Pragma("unroll")                                               \
        for (int h2_ = 0; h2_ < 2; h2_++) {                             \
            int tl_ = tl0_ + h2_ * 16;                                  \
            float v_ = (PJv[0][b_][tl_] + PJv[1][b_][tl_]) +            \
                       (PJv[2][b_][tl_] + PJv[3][b_][tl_]);             \
            __builtin_nontemporal_store(v_, dpt_ + tl_);                \
        }                                                               \
        __syncthreads();                                                \
    }                                                                   \
} while (0)

__global__ __launch_bounds__(NTHR, 2) void k_lstm(
    const ushort_t* __restrict__ wh, const ushort_t* __restrict__ wlo,
    const ushort_t* __restrict__ xh, const ushort_t* __restrict__ xl,
    char* hx,
    const float* __restrict__ bih, const float* __restrict__ bhh,
    const float* __restrict__ convw, float* __restrict__ part)
{
    const int tid = threadIdx.x;
    const int w   = tid >> 6;          // wave 0..3
    const int l   = tid & 63;
    const int gp  = blockIdx.x >> 5;   // gpair 0..1
    const int s   = blockIdx.x & 31;   // hidden slice 0..31 (16 units each)
    const int gA  = gp * 2;            // chain A batch group
    const int gB  = gp * 2 + 1;        // chain B batch group
    const int n   = l & 15;            // A-tile row (u-major: u=n>>2, gate=n&3)
    const int q   = l >> 4;            // quad (k-block; also: unit in epilogue)
    const int j   = s * 16 + w * 4 + q;// hidden unit owned in epilogue
    const int roww = (n & 3) * HID + s * 16 + w * 4 + (n >> 2);
    const int b0A = gA * 16;
    const int b0B = gB * 16;
    const int wg  = s * 4 + w;         // producing-wave id in group, 0..127

    __shared__ u64_t hsA[4096];                // staged h chain A (32 KB)
    __shared__ u64_t hsB[4096];                // staged h chain B (32 KB)
    __shared__ float pjA[4][16][32];           // projection partials (8 KB)
    __shared__ float pjB[4][16][32];           // projection partials (8 KB)

    // W_hi AND W_lo fragments: 17 K-chunks (compiler may rematerialize)
    bf16x8 Bh[17], Bl[17];
    #pragma unroll
    for (int c = 0; c < 17; c++) {
        Bh[c] = *(const bf16x8*)(wh  + roww * KDIM + c * 32 + q * 8);
        Bl[c] = *(const bf16x8*)(wlo + roww * KDIM + c * 32 + q * 8);
    }

    float bias4[4];
    #pragma unroll
    for (int r = 0; r < 4; r++) bias4[r] = bih[r * HID + j] + bhh[r * HID + j];
    const float cw = convw[j];
    float cstA = 0.f, cstB = 0.f;

    // staging decode consts (R20 mapping): packet p = k*256+tid, wg'=p>>4,
    // m=p&15; c=wg'>>3, sq=(wg'>>1)&3, sd=wg'&1
    const int m16 = tid & 15;
    const int hi4 = tid >> 4;
    const int sq  = (hi4 >> 1) & 3, sd = hi4 & 1, chalf = hi4 >> 3;

    __syncthreads();

    union frag { u32x4 u; bf16x8 v; };
    u32x4 hvA[8], hvB[8];
    bf16x8 AxA, LxA, AxB, LxB;

    // ---- prologue: issue chain-A probes (t=0, parity 0) + xA(0) ----
    {
        const char* sA0 = hx + (size_t)gA * 32768 + tid * 16;
        #pragma unroll
        for (int k = 0; k < 8; k++) hvA[k] = cld16(sA0 + k * 4096);
        int xo = (0 * 64 + b0A + n) * 32 + q * 8;
        AxA = *(const bf16x8*)(xh + xo);
        LxA = *(const bf16x8*)(xl + xo);
    }

    for (int t = 0; t < T_STEPS; t++) {
        // ================= chain A phase =================
        const char* srcCA = hx + (size_t)(((t & 1) * 4 + gA)) * 32768 + tid * 16;
        waitvm0();
        __builtin_amdgcn_sched_barrier(0);
        if (t > 0) CHECKPOLL(hvA, srcCA);
        STAGE(hsA, hvA);
        __syncthreads();
        // issue chain-B probes (h_B(t-1), parity t&1) + xB(t): they fly
        // during compute A (~1500 cy)
        {
            const char* sB = hx + (size_t)(((t & 1) * 4 + gB)) * 32768 + tid * 16;
            #pragma unroll
            for (int k = 0; k < 8; k++) hvB[k] = cld16(sB + k * 4096);
            int xo = (t * 64 + b0B + n) * 32 + q * 8;
            AxB = *(const bf16x8*)(xh + xo);
            LxB = *(const bf16x8*)(xl + xo);
        }
        {
            f32x4 a0 = {0,0,0,0}, a1 = {0,0,0,0}, a2 = {0,0,0,0},
                  a3 = {0,0,0,0}, a4 = {0,0,0,0}, a5 = {0,0,0,0};
            #pragma unroll
            for (int c = 0; c < 16; c++) CHUNK(hsA, c);
            a0 = MFMA(Bh[16], AxA, a0);
            a2 = MFMA(Bl[16], AxA, a2);
            a4 = MFMA(Bh[16], LxA, a4);
            f32x4 D = (a0 + a1) + (a2 + a3) + (a4 + a5);
            EPI(D, cstA, gA, pjA);
        }

        // ================= chain B phase =================
        const char* srcCB = hx + (size_t)(((t & 1) * 4 + gB)) * 32768 + tid * 16;
        waitvm0();
        __builtin_amdgcn_sched_barrier(0);
        if (t > 0) CHECKPOLL(hvB, srcCB);
        STAGE(hsB, hvB);
        __syncthreads();
        // issue chain-A probes for t+1 + xA(t+1): they fly during compute B
        if (t + 1 < T_STEPS) {
            const char* sAn = hx + (size_t)((((t + 1) & 1) * 4 + gA)) * 32768 + tid * 16;
            #pragma unroll
            for (int k = 0; k < 8; k++) hvA[k] = cld16(sAn + k * 4096);
            int xo = ((t + 1) * 64 + b0A + n) * 32 + q * 8;
            AxA = *(const bf16x8*)(xh + xo);
            LxA = *(const bf16x8*)(xl + xo);
        }
        {
            f32x4 a0 = {0,0,0,0}, a1 = {0,0,0,0}, a2 = {0,0,0,0},
                  a3 = {0,0,0,0}, a4 = {0,0,0,0}, a5 = {0,0,0,0};
            #pragma unroll
            for (int c = 0; c < 16; c++) CHUNK(hsB, c);
            a0 = MFMA(Bh[16], AxB, a0);
            a2 = MFMA(Bl[16], AxB, a2);
            a4 = MFMA(Bh[16], LxB, a4);
            f32x4 D = (a0 + a1) + (a2 + a3) + (a4 + a5);
            EPI(D, cstB, gB, pjB);
        }
    }
}

extern "C" void kernel_launch(void* const* d_in, const int* in_sizes, int n_in,
                              void* d_out, int out_size, void* d_ws, size_t ws_size,
                              hipStream_t stream) {
    const float* in  = (const float*)d_in[0];
    const float* Wih = (const float*)d_in[1];
    const float* Whh = (const float*)d_in[2];
    const float* bih = (const float*)d_in[3];
    const float* bhh = (const float*)d_in[4];
    const float* cvw = (const float*)d_in[5];
    const float* cvb = (const float*)d_in[6];
    float* out = (float*)d_out;

    char* ws = (char*)d_ws;
    ushort_t* wh  = (ushort_t*)ws; ws += (size_t)2048 * KDIM * 2;      // 2,228,224
    ushort_t* wl  = (ushort_t*)ws; ws += (size_t)2048 * KDIM * 2;
    ushort_t* xh  = (ushort_t*)ws; ws += (size_t)1024 * 64 * 32 * 2;   // 4,194,304
    ushort_t* xl  = (ushort_t*)ws; ws += (size_t)1024 * 64 * 32 * 2;
    char*     hx  = ws;            ws += (size_t)2 * 4 * 128 * 16 * 16;// 262,144
    float*    pp  = (float*)ws;    ws += (size_t)128 * 16 * 1024 * 4;  // 8,388,608
    // total ~21.5 MB of ws

    k_init<<<256, 256, 0, stream>>>((uint_t*)hx);
    k_wcat<<<2048, 256, 0, stream>>>(Wih, Whh, wh, wl);
    k_xbuf<<<512, 256, 0, stream>>>(in, xh, xl);
    k_lstm<<<NBLK, NTHR, 0, stream>>>(wh, wl, xh, xl, hx,
                                      bih, bhh, cvw, pp);
    k_reduce<<<256, 256, 0, stream>>>(pp, out, cvb);
}

// Round 10
// 2991.044 us; speedup vs baseline: 2.5661x; 2.5661x over previous
//
#include <hip/hip_runtime.h>
#include <hip/hip_bf16.h>

// LSTM: B=64, D=32, H=512, T=1024. gates = [h,x] @ [W_hh;W_ih]^T + b_ih + b_hh
// Round 23: R19 base (validated 2905us steady: 64 blocks = 4 groups x 16
// slices, 512 thr, 8 waves, lane-local swapped-MFMA epilogue, sc0sc1
// data-as-flag 4B words, tag bit16 ring-2) + two deltas:
// (1) TWO-PHASE step: poll/stage packets k=0,1 (chunks 0-7) -> bar ->
//     issue k=2,3 probes -> MFMA c0-7 -> waitvm0 (probes had ~990cy flight
//     AND were issued after producers provably published -> first check
//     succeeds) -> stage -> bar -> MFMA c8-15+x -> epilogue. Half the
//     exchange detection hidden under compute. Single hs buffer (each
//     region's write/read epochs separated by one of the two barriers):
//     LDS 32KB hs + 16KB projsh = 48KB.
// (2) Weight residency forced via NAMED registers Bh0..16/Bl0..16 (R19's
//     VGPR_Count=104 proved remat: 272KB/block/step L2 reloads on the
//     critical path). launch_bounds(512,2) caps 256, need ~215.
// Transport/tags/staging math/epilogue byte-identical to R19.

typedef unsigned short ushort_t;
typedef unsigned int   uint_t;
typedef unsigned long long u64_t;
typedef __attribute__((ext_vector_type(8))) short bf16x8;
typedef __attribute__((ext_vector_type(4))) float f32x4;
typedef __attribute__((ext_vector_type(4))) uint_t u32x4;

#define T_STEPS 1024
#define HID     512
#define KDIM    544   // 512 h + 32 x
#define NBLK    64    // 4 groups * 16 slices
#define NTHR    512

__device__ inline ushort_t f2bf(float x) {
    __hip_bfloat16 h = __float2bfloat16(x);
    return *(ushort_t*)&h;
}
__device__ inline float bf2f(ushort_t u) {
    __hip_bfloat16 h = *(__hip_bfloat16*)&u;
    return __bfloat162float(h);
}

__device__ inline f32x4 MFMA(bf16x8 a, bf16x8 b, f32x4 c) {
    return __builtin_amdgcn_mfma_f32_16x16x32_bf16(a, b, c, 0, 0, 0);
}

// coherent 16B load / 4B store (L1+L2 bypass, meets at Infinity Cache)
__device__ inline u32x4 cld16(const void* p) {
    u32x4 v;
    asm volatile("global_load_dwordx4 %0, %1, off sc0 sc1"
                 : "=v"(v) : "v"(p) : "memory");
    return v;
}
__device__ inline void cst4(void* p, uint_t v) {
    asm volatile("global_store_dword %0, %1, off sc0 sc1"
                 :: "v"(p), "v"(v) : "memory");
}
__device__ inline void waitvm0() {
    asm volatile("s_waitcnt vmcnt(0)" ::: "memory");
}

// is_tanh: tanh(v)=(1-e)/(1+e), e=2^(-2.885*v); sigmoid(v)=1/(1+e), e=2^(-1.4427*v)
__device__ inline float act_gate(float v, int is_tanh) {
    float vc = fminf(fmaxf(v, -43.f), 43.f);
    float kk = is_tanh ? -2.88539008f : -1.44269504f;
    float e  = __builtin_exp2f(vc * kk);
    float num = is_tanh ? (1.f - e) : 1.f;
    return num * __builtin_amdgcn_rcpf(1.f + e);
}

// ---------- prep kernels ----------

__global__ void k_init(uint_t* hx32) {
    int i = blockIdx.x * 256 + threadIdx.x;      // grid 256x256 = 65536
    // init h ring: value ~0 (denormal bf16), tag bit16 = 1 (differs from tag 0
    // expected at t=1/t=2) -> no ABA with init data.
    hx32[i] = 0x00010000u;                       // 2*4*128*16 x 16B = 65536 u32
}

__global__ void k_wcat(const float* __restrict__ wih, const float* __restrict__ whh,
                       ushort_t* __restrict__ wh, ushort_t* __restrict__ wl) {
    int r = blockIdx.x;                          // 2048 gate rows
    for (int k = threadIdx.x; k < KDIM; k += 256) {
        float w = (k < 512) ? whh[r * 512 + k] : wih[r * 32 + (k - 512)];
        ushort_t hh = f2bf(w);
        ushort_t ll = f2bf(w - bf2f(hh));
        wh[r * KDIM + k] = hh;
        wl[r * KDIM + k] = ll;
    }
}

// input (B=64, D=32, T=1024) fp32 -> xbuf[t][b][d] bf16 hi/lo
__global__ void k_xbuf(const float* __restrict__ in,
                       ushort_t* __restrict__ xh, ushort_t* __restrict__ xl) {
    __shared__ float tile[64][65];
    int bp = blockIdx.x >> 4;                    // batch pair 0..31
    int tt = blockIdx.x & 15;                    // t tile 0..15
    int t0 = tt * 64;
    int wv = threadIdx.x >> 6, l = threadIdx.x & 63;
    for (int r = wv * 16; r < wv * 16 + 16; r++) {
        int b = bp * 2 + (r >> 5), d = r & 31;
        tile[r][l] = in[(b * 32 + d) * 1024 + t0 + l];
    }
    __syncthreads();
    for (int i = 0; i < 16; i++) {
        int tl = wv * 16 + i;
        float v = tile[l][tl];
        ushort_t hh = f2bf(v);
        ushort_t ll = f2bf(v - bf2f(hh));
        int o = (t0 + tl) * 2048 + bp * 64 + l;  // = t*64*32 + b*32 + d
        xh[o] = hh;
        xl[o] = ll;
    }
}

// out[b][t] = conv_b + sum_s part[(g*16+s)*16 + bl][t]   (b = g*16+bl)
__global__ void k_reduce(const float* __restrict__ part, float* __restrict__ out,
                         const float* __restrict__ cvb) {
    int b = blockIdx.x >> 2;                     // 0..63
    int t = (blockIdx.x & 3) * 256 + threadIdx.x;
    int g = b >> 4, bl = b & 15;
    const float* p = part + ((size_t)(g * 16 * 16 + bl)) * 1024 + t;
    float sum = 0.f;
    #pragma unroll
    for (int s = 0; s < 16; s++) sum += p[(size_t)s * 16 * 1024];
    out[b * 1024 + t] = sum + cvb[0];
}

// ---------- main recurrent kernel ----------

// poll-until-fresh on packets kA,kB (device-scope reload of stale ones)
#define POLL2(kA, kB) do {                                              \
    const uint_t exp_ = ((uint_t)(((t - 1) >> 1) & 1)) << 16;           \
    for (;;) {                                                          \
        bool ok_ = true;                                                \
        if (((hv[kA][0] & 0x10000u) != exp_) ||                         \
            ((hv[kA][1] & 0x10000u) != exp_) ||                         \
            ((hv[kA][2] & 0x10000u) != exp_) ||                         \
            ((hv[kA][3] & 0x10000u) != exp_)) {                         \
            hv[kA] = cld16(srcB + (kA) * 8192);                         \
            ok_ = false;                                                \
        }                                                               \
        if (((hv[kB][0] & 0x10000u) != exp_) ||                         \
            ((hv[kB][1] & 0x10000u) != exp_) ||                         \
            ((hv[kB][2] & 0x10000u) != exp_) ||                         \
            ((hv[kB][3] & 0x10000u) != exp_)) {                         \
            hv[kB] = cld16(srcB + (kB) * 8192);                         \
            ok_ = false;                                                \
        }                                                               \
        if (ok_) break;                                                 \
        __builtin_amdgcn_s_sleep(1);                                    \
        waitvm0();                                                      \
        __builtin_amdgcn_sched_barrier(0);                              \
    }                                                                   \
} while (0)

// stage packet k into LDS, deinterleaving (hi,lo)x4 units
#define STAGE1(k_) do {                                                 \
    uint_t I0 = hv[k_][0], I1 = hv[k_][1];                              \
    uint_t I2 = hv[k_][2], I3 = hv[k_][3];                              \
    uint_t hA_ = __builtin_amdgcn_perm(I1, I0, 0x05040100u);            \
    uint_t hB_ = __builtin_amdgcn_perm(I3, I2, 0x05040100u);            \
    uint_t lA_ = __builtin_amdgcn_perm(I1, I0, 0x07060302u);            \
    uint_t lB_ = __builtin_amdgcn_perm(I3, I2, 0x07060302u);            \
    int c_  = (k_) * 4 + sc0v;                                          \
    int li_ = ((c_ * 4 + sq) * 16 + m16) * 2 + sd;                      \
    hs[li_]        = (u64_t)hA_ | ((u64_t)hB_ << 32);                   \
    hs[li_ + 2048] = (u64_t)lA_ | ((u64_t)lB_ << 32);                   \
} while (0)

// one MFMA K-chunk from LDS; weights are NAMED registers Bh<c>/Bl<c>
#define CHUNK(c) do {                                                   \
    frag Ah_, Al_;                                                      \
    int li_ = (((c) * 4 + q) * 16 + n) * 2;                             \
    Ah_.v = *(const bf16x8*)&hs[li_];                                   \
    Al_.v = *(const bf16x8*)&hs[li_ + 2048];                            \
    if ((c) & 1) {                                                      \
        a1 = MFMA(Bh##c, Ah_.v, a1);                                    \
        a3 = MFMA(Bl##c, Ah_.v, a3);                                    \
        a5 = MFMA(Bh##c, Al_.v, a5);                                    \
    } else {                                                            \
        a0 = MFMA(Bh##c, Ah_.v, a0);                                    \
        a2 = MFMA(Bl##c, Ah_.v, a2);                                    \
        a4 = MFMA(Bh##c, Al_.v, a4);                                    \
    }                                                                   \
} while (0)

#define DECLW(c)                                                        \
    const bf16x8 Bh##c = *(const bf16x8*)(wbh + (c) * 32);              \
    const bf16x8 Bl##c = *(const bf16x8*)(wbl + (c) * 32);

__global__ __launch_bounds__(NTHR, 2) void k_lstm(
    const ushort_t* __restrict__ wh, const ushort_t* __restrict__ wlo,
    const ushort_t* __restrict__ xh, const ushort_t* __restrict__ xl,
    char* hx,
    const float* __restrict__ bih, const float* __restrict__ bhh,
    const float* __restrict__ convw, float* __restrict__ part)
{
    const int tid = threadIdx.x;
    const int w   = tid >> 6;          // wave 0..7
    const int l   = tid & 63;
    const int g   = blockIdx.x >> 4;   // batch group 0..3
    const int s   = blockIdx.x & 15;   // hidden slice 0..15 (32 units each)
    const int n   = l & 15;            // A-tile row (u-major: u=n>>2, gate=n&3)
    const int q   = l >> 4;            // quad (k-block; also: unit in epilogue)
    const int j   = s * 32 + w * 4 + q;// hidden unit owned in epilogue
    // weight row for the A-operand, tile rows ordered unit-major
    const int roww = (n & 3) * HID + s * 32 + w * 4 + (n >> 2);
    const int b0  = g * 16;
    const int wg  = s * 8 + w;         // producing-wave id in group, 0..127

    __shared__ u64_t hs[4096];                 // staged h, single buf (32 KB)
    __shared__ float projsh[8][16][32];        // projection partials (16 KB)

    // W_hi AND W_lo fragments as NAMED registers (17 K-chunks each)
    const ushort_t* wbh = wh  + roww * KDIM + q * 8;
    const ushort_t* wbl = wlo + roww * KDIM + q * 8;
    DECLW(0)  DECLW(1)  DECLW(2)  DECLW(3)  DECLW(4)  DECLW(5)
    DECLW(6)  DECLW(7)  DECLW(8)  DECLW(9)  DECLW(10) DECLW(11)
    DECLW(12) DECLW(13) DECLW(14) DECLW(15) DECLW(16)

    // epilogue constants: lane (q,n) owns unit j, batch n -> 4 gate biases
    float bias4[4];
    #pragma unroll
    for (int r = 0; r < 4; r++) bias4[r] = bih[r * HID + j] + bhh[r * HID + j];
    const float cw = convw[j];
    float cst = 0.f;                   // c-state: one (unit, batch) per lane

    // staging mapping: packet p = k*512+tid (k=0..3) -> wg' = p>>4, m = p&15
    // c = k*4 + (hi5>>3), sq = (hi5>>1)&3, sd = hi5&1   (chunk c <- slice s=c)
    const int m16 = tid & 15;
    const int hi5 = tid >> 4;
    const int sq  = (hi5 >> 1) & 3, sd = hi5 & 1, sc0v = hi5 >> 3;

    __syncthreads();

    union frag { u64_t d[2]; bf16x8 v; };

    for (int t = 0; t < T_STEPS; t++) {
        bf16x8 Ax, Lx;
        // x fragment (B-operand: lane (q,n) = x[batch n][dims q*8..+8])
        {
            int xo = (t * 64 + b0 + n) * 32 + q * 8;
            Ax = *(const bf16x8*)(xh + xo);
            Lx = *(const bf16x8*)(xl + xo);
        }

        // ================== phase 1: chunks 0..7 ==================
        const char* srcB = hx + (size_t)(((t & 1) * 4 + g)) * 32768 + tid * 16;
        u32x4 hv[4];
        hv[0] = cld16(srcB);
        hv[1] = cld16(srcB + 8192);
        waitvm0();
        __builtin_amdgcn_sched_barrier(0);
        if (t > 0) POLL2(0, 1);
        STAGE1(0);
        STAGE1(1);
        __syncthreads();

        // issue half-1 probes NOW: producers provably published (phase-1
        // poll succeeded -> all peers passed their previous epilogue), and
        // the probes get the whole phase-1 MFMA (~1000cy) of flight time.
        hv[2] = cld16(srcB + 16384);
        hv[3] = cld16(srcB + 24576);

        f32x4 a0 = {0,0,0,0}, a1 = {0,0,0,0}, a2 = {0,0,0,0},
              a3 = {0,0,0,0}, a4 = {0,0,0,0}, a5 = {0,0,0,0};
        CHUNK(0); CHUNK(1); CHUNK(2); CHUNK(3);
        CHUNK(4); CHUNK(5); CHUNK(6); CHUNK(7);

        // ================== phase 2: chunks 8..15 + x ==================
        waitvm0();                       // probes done (had ~1000cy flight)
        __builtin_amdgcn_sched_barrier(0);
        if (t > 0) POLL2(2, 3);
        STAGE1(2);
        STAGE1(3);
        __syncthreads();

        CHUNK(8);  CHUNK(9);  CHUNK(10); CHUNK(11);
        CHUNK(12); CHUNK(13); CHUNK(14); CHUNK(15);
        {   // x chunk (c=16)
            a0 = MFMA(Bh16, Ax, a0);
            a2 = MFMA(Bl16, Ax, a2);
            a4 = MFMA(Bh16, Lx, a4);
        }
        f32x4 D = (a0 + a1) + (a2 + a3) + (a4 + a5);

        // ---- lane-local epilogue: D[r] = gate r of (unit j, batch n) ----
        char* dstB = hx + (size_t)((((t + 1) & 1) * 4 + g) * 128 + wg) * 256;
        const uint_t tag32 = ((uint_t)((t >> 1) & 1)) << 16;
        float iv = act_gate(D[0] + bias4[0], 0);
        float fv = act_gate(D[1] + bias4[1], 0);
        float gv = act_gate(D[2] + bias4[2], 1);
        float ov = act_gate(D[3] + bias4[3], 0);
        float cc = fv * cst + iv * gv;
        cst = cc;
        float th = act_gate(cc, 1);
        float h  = ov * th;
        float pr = cw * h;
        {
            ushort_t hb = f2bf(h);
            uint_t hvp = (uint_t)hb;
            uint_t lvp = (uint_t)f2bf(h - bf2f(hb));
            uint_t word = (hvp | (lvp << 16)) & ~0x10000u;
            word |= tag32;                       // every word self-tagged
            // packet layout: wg*256 + batch*16 + unit*4 (identical to R13)
            cst4(dstB + n * 16 + q * 4, word);
        }
        // NO drain, NO flag: tagged data IS the publication.

        // projection partial (off critical path): sum over the wave's 4 units
        pr += __shfl_xor(pr, 16);
        pr += __shfl_xor(pr, 32);
        if (l < 16) projsh[w][l][t & 31] = pr;   // l==n when q==0
        if ((t & 31) == 31) {
            __syncthreads();
            // 512 entries (16 batches x 32 steps), one per thread
            int b = tid >> 5, tl = tid & 31;
            float v = ((projsh[0][b][tl] + projsh[1][b][tl]) +
                       (projsh[2][b][tl] + projsh[3][b][tl])) +
                      ((projsh[4][b][tl] + projsh[5][b][tl]) +
                       (projsh[6][b][tl] + projsh[7][b][tl]));
            float* dpt = part + (size_t)((g * 16 + s) * 16 + b) * 1024 + (t - 31);
            __builtin_nontemporal_store(v, dpt + tl);
            __syncthreads();
        }
    }
}

extern "C" void kernel_launch(void* const* d_in, const int* in_sizes, int n_in,
                              void* d_out, int out_size, void* d_ws, size_t ws_size,
                              hipStream_t stream) {
    const float* in  = (const float*)d_in[0];
    const float* Wih = (const float*)d_in[1];
    const float* Whh = (const float*)d_in[2];
    const float* bih = (const float*)d_in[3];
    const float* bhh = (const float*)d_in[4];
    const float* cvw = (const float*)d_in[5];
    const float* cvb = (const float*)d_in[6];
    float* out = (float*)d_out;

    char* ws = (char*)d_ws;
    ushort_t* wh  = (ushort_t*)ws; ws += (size_t)2048 * KDIM * 2;      // 2,228,224
    ushort_t* wl  = (ushort_t*)ws; ws += (size_t)2048 * KDIM * 2;
    ushort_t* xh  = (ushort_t*)ws; ws += (size_t)1024 * 64 * 32 * 2;   // 4,194,304
    ushort_t* xl  = (ushort_t*)ws; ws += (size_t)1024 * 64 * 32 * 2;
    char*     hx  = ws;            ws += (size_t)2 * 4 * 128 * 16 * 16;// 262,144
    float*    pp  = (float*)ws;    ws += (size_t)64 * 16 * 1024 * 4;   // 4,194,304
    // total ~17.3 MB of ws

    k_init<<<256, 256, 0, stream>>>((uint_t*)hx);
    k_wcat<<<2048, 256, 0, stream>>>(Wih, Whh, wh, wl);
    k_xbuf<<<512, 256, 0, stream>>>(in, xh, xl);
    k_lstm<<<NBLK, NTHR, 0, stream>>>(wh, wl, xh, xl, hx,
                                      bih, bhh, cvw, pp);
    k_reduce<<<256, 256, 0, stream>>>(pp, out, cvb);
}

// Round 11
// 2933.184 us; speedup vs baseline: 2.6167x; 1.0197x over previous
//
#include <hip/hip_runtime.h>
#include <hip/hip_bf16.h>

// LSTM: B=64, D=32, H=512, T=1024. gates = [h,x] @ [W_hh;W_ih]^T + b_ih + b_hh
// Round 24: R23 (two-phase step, validated 2938us) + ASM-LOADED WEIGHT
// REGISTERS. R23's VGPR_Count=116 proved the 34 weight fragments were being
// reloaded from L2 every step: every transport asm has a "memory" clobber,
// which invalidates compiler-cached loads -> ~278KB/block/step L2 traffic +
// waitcnt chains on the critical path. Fix: weights loaded via asm
// global_load_dwordx4 WITHOUT memory clobber -> opaque SSA register values
// the compiler cannot rematerialize (black box), so they stay in VGPRs for
// the whole kernel. Manual waitvm0 + sched_barrier(0) after the 34 loads
// (compiler doesn't track vmcnt for asm loads, rule 18). Everything else
// byte-identical to R23: 64 blocks = 4 groups x 16 slices, 512 thr, 8 waves,
// two-phase poll/stage/MFMA, lane-local epilogue, sc0sc1 data-as-flag 4B
// words, tag bit16 ring-2. LDS 48KB. launch_bounds(512,2) caps VGPR at 256
// (need ~220).

typedef unsigned short ushort_t;
typedef unsigned int   uint_t;
typedef unsigned long long u64_t;
typedef __attribute__((ext_vector_type(8))) short bf16x8;
typedef __attribute__((ext_vector_type(4))) float f32x4;
typedef __attribute__((ext_vector_type(4))) uint_t u32x4;

#define T_STEPS 1024
#define HID     512
#define KDIM    544   // 512 h + 32 x
#define NBLK    64    // 4 groups * 16 slices
#define NTHR    512

__device__ inline ushort_t f2bf(float x) {
    __hip_bfloat16 h = __float2bfloat16(x);
    return *(ushort_t*)&h;
}
__device__ inline float bf2f(ushort_t u) {
    __hip_bfloat16 h = *(__hip_bfloat16*)&u;
    return __bfloat162float(h);
}

__device__ inline f32x4 MFMA(bf16x8 a, bf16x8 b, f32x4 c) {
    return __builtin_amdgcn_mfma_f32_16x16x32_bf16(a, b, c, 0, 0, 0);
}

// coherent 16B load / 4B store (L1+L2 bypass, meets at Infinity Cache)
__device__ inline u32x4 cld16(const void* p) {
    u32x4 v;
    asm volatile("global_load_dwordx4 %0, %1, off sc0 sc1"
                 : "=v"(v) : "v"(p) : "memory");
    return v;
}
__device__ inline void cst4(void* p, uint_t v) {
    asm volatile("global_store_dword %0, %1, off sc0 sc1"
                 :: "v"(p), "v"(v) : "memory");
}
__device__ inline void waitvm0() {
    asm volatile("s_waitcnt vmcnt(0)" ::: "memory");
}
// register-pinned 16B load: NO memory clobber -> result is an opaque SSA
// value the compiler keeps in VGPRs (cannot rematerialize an asm result).
__device__ inline bf16x8 ald16(const void* p) {
    bf16x8 v;
    asm volatile("global_load_dwordx4 %0, %1, off"
                 : "=v"(v) : "v"(p));
    return v;
}

// is_tanh: tanh(v)=(1-e)/(1+e), e=2^(-2.885*v); sigmoid(v)=1/(1+e), e=2^(-1.4427*v)
__device__ inline float act_gate(float v, int is_tanh) {
    float vc = fminf(fmaxf(v, -43.f), 43.f);
    float kk = is_tanh ? -2.88539008f : -1.44269504f;
    float e  = __builtin_exp2f(vc * kk);
    float num = is_tanh ? (1.f - e) : 1.f;
    return num * __builtin_amdgcn_rcpf(1.f + e);
}

// ---------- prep kernels ----------

__global__ void k_init(uint_t* hx32) {
    int i = blockIdx.x * 256 + threadIdx.x;      // grid 256x256 = 65536
    // init h ring: value ~0 (denormal bf16), tag bit16 = 1 (differs from tag 0
    // expected at t=1/t=2) -> no ABA with init data.
    hx32[i] = 0x00010000u;                       // 2*4*128*16 x 16B = 65536 u32
}

__global__ void k_wcat(const float* __restrict__ wih, const float* __restrict__ whh,
                       ushort_t* __restrict__ wh, ushort_t* __restrict__ wl) {
    int r = blockIdx.x;                          // 2048 gate rows
    for (int k = threadIdx.x; k < KDIM; k += 256) {
        float w = (k < 512) ? whh[r * 512 + k] : wih[r * 32 + (k - 512)];
        ushort_t hh = f2bf(w);
        ushort_t ll = f2bf(w - bf2f(hh));
        wh[r * KDIM + k] = hh;
        wl[r * KDIM + k] = ll;
    }
}

// input (B=64, D=32, T=1024) fp32 -> xbuf[t][b][d] bf16 hi/lo
__global__ void k_xbuf(const float* __restrict__ in,
                       ushort_t* __restrict__ xh, ushort_t* __restrict__ xl) {
    __shared__ float tile[64][65];
    int bp = blockIdx.x >> 4;                    // batch pair 0..31
    int tt = blockIdx.x & 15;                    // t tile 0..15
    int t0 = tt * 64;
    int wv = threadIdx.x >> 6, l = threadIdx.x & 63;
    for (int r = wv * 16; r < wv * 16 + 16; r++) {
        int b = bp * 2 + (r >> 5), d = r & 31;
        tile[r][l] = in[(b * 32 + d) * 1024 + t0 + l];
    }
    __syncthreads();
    for (int i = 0; i < 16; i++) {
        int tl = wv * 16 + i;
        float v = tile[l][tl];
        ushort_t hh = f2bf(v);
        ushort_t ll = f2bf(v - bf2f(hh));
        int o = (t0 + tl) * 2048 + bp * 64 + l;  // = t*64*32 + b*32 + d
        xh[o] = hh;
        xl[o] = ll;
    }
}

// out[b][t] = conv_b + sum_s part[(g*16+s)*16 + bl][t]   (b = g*16+bl)
__global__ void k_reduce(const float* __restrict__ part, float* __restrict__ out,
                         const float* __restrict__ cvb) {
    int b = blockIdx.x >> 2;                     // 0..63
    int t = (blockIdx.x & 3) * 256 + threadIdx.x;
    int g = b >> 4, bl = b & 15;
    const float* p = part + ((size_t)(g * 16 * 16 + bl)) * 1024 + t;
    float sum = 0.f;
    #pragma unroll
    for (int s = 0; s < 16; s++) sum += p[(size_t)s * 16 * 1024];
    out[b * 1024 + t] = sum + cvb[0];
}

// ---------- main recurrent kernel ----------

// poll-until-fresh on packets kA,kB (device-scope reload of stale ones)
#define POLL2(kA, kB) do {                                              \
    const uint_t exp_ = ((uint_t)(((t - 1) >> 1) & 1)) << 16;           \
    for (;;) {                                                          \
        bool ok_ = true;                                                \
        if (((hv[kA][0] & 0x10000u) != exp_) ||                         \
            ((hv[kA][1] & 0x10000u) != exp_) ||                         \
            ((hv[kA][2] & 0x10000u) != exp_) ||                         \
            ((hv[kA][3] & 0x10000u) != exp_)) {                         \
            hv[kA] = cld16(srcB + (kA) * 8192);                         \
            ok_ = false;                                                \
        }                                                               \
        if (((hv[kB][0] & 0x10000u) != exp_) ||                         \
            ((hv[kB][1] & 0x10000u) != exp_) ||                         \
            ((hv[kB][2] & 0x10000u) != exp_) ||                         \
            ((hv[kB][3] & 0x10000u) != exp_)) {                         \
            hv[kB] = cld16(srcB + (kB) * 8192);                         \
            ok_ = false;                                                \
        }                                                               \
        if (ok_) break;                                                 \
        __builtin_amdgcn_s_sleep(1);                                    \
        waitvm0();                                                      \
        __builtin_amdgcn_sched_barrier(0);                              \
    }                                                                   \
} while (0)

// stage packet k into LDS, deinterleaving (hi,lo)x4 units
#define STAGE1(k_) do {                                                 \
    uint_t I0 = hv[k_][0], I1 = hv[k_][1];                              \
    uint_t I2 = hv[k_][2], I3 = hv[k_][3];                              \
    uint_t hA_ = __builtin_amdgcn_perm(I1, I0, 0x05040100u);            \
    uint_t hB_ = __builtin_amdgcn_perm(I3, I2, 0x05040100u);            \
    uint_t lA_ = __builtin_amdgcn_perm(I1, I0, 0x07060302u);            \
    uint_t lB_ = __builtin_amdgcn_perm(I3, I2, 0x07060302u);            \
    int c_  = (k_) * 4 + sc0v;                                          \
    int li_ = ((c_ * 4 + sq) * 16 + m16) * 2 + sd;                      \
    hs[li_]        = (u64_t)hA_ | ((u64_t)hB_ << 32);                   \
    hs[li_ + 2048] = (u64_t)lA_ | ((u64_t)lB_ << 32);                   \
} while (0)

// one MFMA K-chunk from LDS; weights are asm-pinned registers Bh<c>/Bl<c>
#define CHUNK(c) do {                                                   \
    frag Ah_, Al_;                                                      \
    int li_ = (((c) * 4 + q) * 16 + n) * 2;                             \
    Ah_.v = *(const bf16x8*)&hs[li_];                                   \
    Al_.v = *(const bf16x8*)&hs[li_ + 2048];                            \
    if ((c) & 1) {                                                      \
        a1 = MFMA(Bh##c, Ah_.v, a1);                                    \
        a3 = MFMA(Bl##c, Ah_.v, a3);                                    \
        a5 = MFMA(Bh##c, Al_.v, a5);                                    \
    } else {                                                            \
        a0 = MFMA(Bh##c, Ah_.v, a0);                                    \
        a2 = MFMA(Bl##c, Ah_.v, a2);                                    \
        a4 = MFMA(Bh##c, Al_.v, a4);                                    \
    }                                                                   \
} while (0)

#define DECLW(c)                                                        \
    const bf16x8 Bh##c = ald16(wbh + (c) * 32);                         \
    const bf16x8 Bl##c = ald16(wbl + (c) * 32);

__global__ __launch_bounds__(NTHR, 2) void k_lstm(
    const ushort_t* __restrict__ wh, const ushort_t* __restrict__ wlo,
    const ushort_t* __restrict__ xh, const ushort_t* __restrict__ xl,
    char* hx,
    const float* __restrict__ bih, const float* __restrict__ bhh,
    const float* __restrict__ convw, float* __restrict__ part)
{
    const int tid = threadIdx.x;
    const int w   = tid >> 6;          // wave 0..7
    const int l   = tid & 63;
    const int g   = blockIdx.x >> 4;   // batch group 0..3
    const int s   = blockIdx.x & 15;   // hidden slice 0..15 (32 units each)
    const int n   = l & 15;            // A-tile row (u-major: u=n>>2, gate=n&3)
    const int q   = l >> 4;            // quad (k-block; also: unit in epilogue)
    const int j   = s * 32 + w * 4 + q;// hidden unit owned in epilogue
    // weight row for the A-operand, tile rows ordered unit-major
    const int roww = (n & 3) * HID + s * 32 + w * 4 + (n >> 2);
    const int b0  = g * 16;
    const int wg  = s * 8 + w;         // producing-wave id in group, 0..127

    __shared__ u64_t hs[4096];                 // staged h, single buf (32 KB)
    __shared__ float projsh[8][16][32];        // projection partials (16 KB)

    // W_hi AND W_lo fragments as asm-pinned registers (17 K-chunks each).
    // ald16 has no memory clobber: the compiler keeps these in VGPRs for the
    // whole kernel (cannot rematerialize an asm result after later clobbers).
    const ushort_t* wbh = wh  + roww * KDIM + q * 8;
    const ushort_t* wbl = wlo + roww * KDIM + q * 8;
    DECLW(0)  DECLW(1)  DECLW(2)  DECLW(3)  DECLW(4)  DECLW(5)
    DECLW(6)  DECLW(7)  DECLW(8)  DECLW(9)  DECLW(10) DECLW(11)
    DECLW(12) DECLW(13) DECLW(14) DECLW(15) DECLW(16)
    waitvm0();                         // asm loads are untracked: drain now
    __builtin_amdgcn_sched_barrier(0);

    // epilogue constants: lane (q,n) owns unit j, batch n -> 4 gate biases
    float bias4[4];
    #pragma unroll
    for (int r = 0; r < 4; r++) bias4[r] = bih[r * HID + j] + bhh[r * HID + j];
    const float cw = convw[j];
    float cst = 0.f;                   // c-state: one (unit, batch) per lane

    // staging mapping: packet p = k*512+tid (k=0..3) -> wg' = p>>4, m = p&15
    // c = k*4 + (hi5>>3), sq = (hi5>>1)&3, sd = hi5&1   (chunk c <- slice s=c)
    const int m16 = tid & 15;
    const int hi5 = tid >> 4;
    const int sq  = (hi5 >> 1) & 3, sd = hi5 & 1, sc0v = hi5 >> 3;

    __syncthreads();

    union frag { u64_t d[2]; bf16x8 v; };

    for (int t = 0; t < T_STEPS; t++) {
        bf16x8 Ax, Lx;
        // x fragment (B-operand: lane (q,n) = x[batch n][dims q*8..+8])
        {
            int xo = (t * 64 + b0 + n) * 32 + q * 8;
            Ax = *(const bf16x8*)(xh + xo);
            Lx = *(const bf16x8*)(xl + xo);
        }

        // ================== phase 1: chunks 0..7 ==================
        const char* srcB = hx + (size_t)(((t & 1) * 4 + g)) * 32768 + tid * 16;
        u32x4 hv[4];
        hv[0] = cld16(srcB);
        hv[1] = cld16(srcB + 8192);
        waitvm0();
        __builtin_amdgcn_sched_barrier(0);
        if (t > 0) POLL2(0, 1);
        STAGE1(0);
        STAGE1(1);
        __syncthreads();

        // issue half-1 probes NOW: producers provably published (phase-1
        // poll succeeded -> all peers passed their previous epilogue), and
        // the probes get the whole phase-1 MFMA (~1000cy) of flight time.
        hv[2] = cld16(srcB + 16384);
        hv[3] = cld16(srcB + 24576);

        f32x4 a0 = {0,0,0,0}, a1 = {0,0,0,0}, a2 = {0,0,0,0},
              a3 = {0,0,0,0}, a4 = {0,0,0,0}, a5 = {0,0,0,0};
        CHUNK(0); CHUNK(1); CHUNK(2); CHUNK(3);
        CHUNK(4); CHUNK(5); CHUNK(6); CHUNK(7);

        // ================== phase 2: chunks 8..15 + x ==================
        waitvm0();                       // probes done (had ~1000cy flight)
        __builtin_amdgcn_sched_barrier(0);
        if (t > 0) POLL2(2, 3);
        STAGE1(2);
        STAGE1(3);
        __syncthreads();

        CHUNK(8);  CHUNK(9);  CHUNK(10); CHUNK(11);
        CHUNK(12); CHUNK(13); CHUNK(14); CHUNK(15);
        {   // x chunk (c=16)
            a0 = MFMA(Bh16, Ax, a0);
            a2 = MFMA(Bl16, Ax, a2);
            a4 = MFMA(Bh16, Lx, a4);
        }
        f32x4 D = (a0 + a1) + (a2 + a3) + (a4 + a5);

        // ---- lane-local epilogue: D[r] = gate r of (unit j, batch n) ----
        char* dstB = hx + (size_t)((((t + 1) & 1) * 4 + g) * 128 + wg) * 256;
        const uint_t tag32 = ((uint_t)((t >> 1) & 1)) << 16;
        float iv = act_gate(D[0] + bias4[0], 0);
        float fv = act_gate(D[1] + bias4[1], 0);
        float gv = act_gate(D[2] + bias4[2], 1);
        float ov = act_gate(D[3] + bias4[3], 0);
        float cc = fv * cst + iv * gv;
        cst = cc;
        float th = act_gate(cc, 1);
        float h  = ov * th;
        float pr = cw * h;
        {
            ushort_t hb = f2bf(h);
            uint_t hvp = (uint_t)hb;
            uint_t lvp = (uint_t)f2bf(h - bf2f(hb));
            uint_t word = (hvp | (lvp << 16)) & ~0x10000u;
            word |= tag32;                       // every word self-tagged
            // packet layout: wg*256 + batch*16 + unit*4 (identical to R13)
            cst4(dstB + n * 16 + q * 4, word);
        }
        // NO drain, NO flag: tagged data IS the publication.

        // projection partial (off critical path): sum over the wave's 4 units
        pr += __shfl_xor(pr, 16);
        pr += __shfl_xor(pr, 32);
        if (l < 16) projsh[w][l][t & 31] = pr;   // l==n when q==0
        if ((t & 31) == 31) {
            __syncthreads();
            // 512 entries (16 batches x 32 steps), one per thread
            int b = tid >> 5, tl = tid & 31;
            float v = ((projsh[0][b][tl] + projsh[1][b][tl]) +
                       (projsh[2][b][tl] + projsh[3][b][tl])) +
                      ((projsh[4][b][tl] + projsh[5][b][tl]) +
                       (projsh[6][b][tl] + projsh[7][b][tl]));
            float* dpt = part + (size_t)((g * 16 + s) * 16 + b) * 1024 + (t - 31);
            __builtin_nontemporal_store(v, dpt + tl);
            __syncthreads();
        }
    }
}

extern "C" void kernel_launch(void* const* d_in, const int* in_sizes, int n_in,
                              void* d_out, int out_size, void* d_ws, size_t ws_size,
                              hipStream_t stream) {
    const float* in  = (const float*)d_in[0];
    const float* Wih = (const float*)d_in[1];
    const float* Whh = (const float*)d_in[2];
    const float* bih = (const float*)d_in[3];
    const float* bhh = (const float*)d_in[4];
    const float* cvw = (const float*)d_in[5];
    const float* cvb = (const float*)d_in[6];
    float* out = (float*)d_out;

    char* ws = (char*)d_ws;
    ushort_t* wh  = (ushort_t*)ws; ws += (size_t)2048 * KDIM * 2;      // 2,228,224
    ushort_t* wl  = (ushort_t*)ws; ws += (size_t)2048 * KDIM * 2;
    ushort_t* xh  = (ushort_t*)ws; ws += (size_t)1024 * 64 * 32 * 2;   // 4,194,304
    ushort_t* xl  = (ushort_t*)ws; ws += (size_t)1024 * 64 * 32 * 2;
    char*     hx  = ws;            ws += (size_t)2 * 4 * 128 * 16 * 16;// 262,144
    float*    pp  = (float*)ws;    ws += (size_t)64 * 16 * 1024 * 4;   // 4,194,304
    // total ~17.3 MB of ws

    k_init<<<256, 256, 0, stream>>>((uint_t*)hx);
    k_wcat<<<2048, 256, 0, stream>>>(Wih, Whh, wh, wl);
    k_xbuf<<<512, 256, 0, stream>>>(in, xh, xl);
    k_lstm<<<NBLK, NTHR, 0, stream>>>(wh, wl, xh, xl, hx,
                                      bih, bhh, cvw, pp);
    k_reduce<<<256, 256, 0, stream>>>(pp, out, cvb);
}